// Round 1
// 689.136 us; speedup vs baseline: 1.0670x; 1.0670x over previous
//
#include <hip/hip_runtime.h>
#include <hip/hip_bf16.h>
#include <stdint.h>

#define NTOK 4096
#define EMBD 1024
#define NEXP 8
#define HIDD 2048
#define NPAIR (NTOK * 2)
#define MBMAX 71  // sum_e ceil(n_e/128) <= 8192/128 + 7

typedef __attribute__((ext_vector_type(8))) __bf16 bf16x8;
typedef __attribute__((ext_vector_type(4))) float f32x4;

union V16 { uint4 u; bf16x8 b; };

__device__ __forceinline__ uint16_t f2bf(float f) {
    uint32_t u = __float_as_uint(f);
    return (uint16_t)((u + 0x7FFFu + ((u >> 16) & 1u)) >> 16);
}
__device__ __forceinline__ float bf2f(uint16_t u) {
    return __uint_as_float(((uint32_t)u) << 16);
}
__device__ __forceinline__ void gl_lds16(const uint16_t* g, uint16_t* l) {
    __builtin_amdgcn_global_load_lds(
        (const __attribute__((address_space(1))) void*)g,
        (__attribute__((address_space(3))) void*)l, 16, 0, 0);
}

// ---- fused router (4 tokens/block, 1 wave each) + transpose-cast of 3 weight
// tensors. Independent work in ONE dispatch to overlap instead of serialize. ----
#define RT_BLOCKS (NTOK / 4)
#define W1_TILES 4096   // (2048/64)*(1024/64)*8
#define WG_TILES 8192   // (2048/64)*(2048/64)*8
#define W2_TILES 4096   // (1024/64)*(2048/64)*8

__global__ __launch_bounds__(256) void fused_rt_kernel(
    const float* __restrict__ x, const float* __restrict__ Wr,
    const float* __restrict__ br, uint16_t* __restrict__ xb,
    int* __restrict__ counts, int* __restrict__ pair_e, float* __restrict__ pair_p,
    const float* __restrict__ W1, const float* __restrict__ Wg,
    const float* __restrict__ W2, uint16_t* __restrict__ W1t,
    uint16_t* __restrict__ Wgt, uint16_t* __restrict__ W2t) {
    int bid = blockIdx.x;
    if (bid < RT_BLOCKS) {
        // ---------------- router ----------------
        int tok = bid * 4 + (threadIdx.x >> 6);
        int lane = threadIdx.x & 63;
        const float* xr = x + (size_t)tok * EMBD;
        uint16_t* xbr = xb + (size_t)tok * EMBD;
        float acc[NEXP];
#pragma unroll
        for (int e = 0; e < NEXP; e++) acc[e] = 0.f;
        for (int d = lane; d < EMBD; d += 64) {
            float xv = xr[d];
            xbr[d] = f2bf(xv);
#pragma unroll
            for (int e = 0; e < NEXP; e++) acc[e] += xv * Wr[d * NEXP + e];
        }
#pragma unroll
        for (int e = 0; e < NEXP; e++) {
#pragma unroll
            for (int off = 32; off > 0; off >>= 1)
                acc[e] += __shfl_down(acc[e], off, 64);
        }
        if (lane == 0) {
            float lg[NEXP];
#pragma unroll
            for (int e = 0; e < NEXP; e++) lg[e] = acc[e] + br[e];
            int e0 = 0;
#pragma unroll
            for (int e = 1; e < NEXP; e++) if (lg[e] > lg[e0]) e0 = e;
            int e1 = (e0 == 0) ? 1 : 0;
#pragma unroll
            for (int e = 0; e < NEXP; e++) if (e != e0 && lg[e] > lg[e1]) e1 = e;
            float mx = lg[0];
#pragma unroll
            for (int e = 1; e < NEXP; e++) mx = fmaxf(mx, lg[e]);
            float s = 0.f, p[NEXP];
#pragma unroll
            for (int e = 0; e < NEXP; e++) { p[e] = __expf(lg[e] - mx); s += p[e]; }
            float inv = 1.f / s;
            pair_e[tok * 2 + 0] = e0; pair_p[tok * 2 + 0] = p[e0] * inv;
            pair_e[tok * 2 + 1] = e1; pair_p[tok * 2 + 1] = p[e1] * inv;
            atomicAdd(&counts[e0], 1);
            atomicAdd(&counts[e1], 1);
        }
        return;
    }
    // ---------------- transpose-cast: src [E][K][N] fp32 -> dst [E][N][K] bf16 ----
    int id = bid - RT_BLOCKS;
    const float* src; uint16_t* dst; int K, N;
    if (id < W1_TILES) { src = W1; dst = W1t; K = EMBD; N = HIDD; }
    else if (id < W1_TILES + WG_TILES) { id -= W1_TILES; src = Wg; dst = Wgt; K = HIDD; N = HIDD; }
    else { id -= W1_TILES + WG_TILES; src = W2; dst = W2t; K = HIDD; N = EMBD; }
    int tn = N >> 6, tk = K >> 6;
    int per_e = tn * tk;
    int e = id / per_e, r = id % per_e;
    int n0 = (r % tn) * 64, k0 = (r / tn) * 64;

    __shared__ uint16_t tile[64][68];
    const float* S = src + ((size_t)e * K + k0) * N + n0;
    uint16_t* D = dst + ((size_t)e * N + n0) * K + k0;
    int t = threadIdx.x;
    int rn = (t & 15) * 4, rk = t >> 4;
#pragma unroll
    for (int p = 0; p < 4; p++) {
        int k = rk + p * 16;
        float4 v = *(const float4*)(S + (size_t)k * N + rn);
        ushort4 o;
        o.x = f2bf(v.x); o.y = f2bf(v.y); o.z = f2bf(v.z); o.w = f2bf(v.w);
        *(ushort4*)&tile[k][rn] = o;
    }
    __syncthreads();
    int wn = t >> 3, wk = (t & 7) * 8;
#pragma unroll
    for (int p = 0; p < 2; p++) {
        int n = wn + p * 32;
        uint32_t w0 = (uint32_t)tile[wk + 0][n] | ((uint32_t)tile[wk + 1][n] << 16);
        uint32_t w1 = (uint32_t)tile[wk + 2][n] | ((uint32_t)tile[wk + 3][n] << 16);
        uint32_t w2 = (uint32_t)tile[wk + 4][n] | ((uint32_t)tile[wk + 5][n] << 16);
        uint32_t w3 = (uint32_t)tile[wk + 6][n] | ((uint32_t)tile[wk + 7][n] << 16);
        uint4 pk = {w0, w1, w2, w3};
        *(uint4*)(D + (size_t)n * K + wk) = pk;
    }
}

// ---- scatter (computes offsets locally from counts) ----
__global__ __launch_bounds__(256) void scatter_kernel(const int* __restrict__ pair_e,
                                                      const int* __restrict__ counts,
                                                      int* __restrict__ cursors,
                                                      int* __restrict__ toklist,
                                                      int* __restrict__ posmap) {
    int i = blockIdx.x * 256 + threadIdx.x;  // pair index
    int e = pair_e[i];
    int offs = 0;
    for (int j = 0; j < NEXP; j++) offs += (j < e) ? counts[j] : 0;
    int pos = offs + atomicAdd(&cursors[e], 1);
    toklist[pos] = i >> 1;
    posmap[i] = pos;
}

// ---- grouped GEMM: 128x128 tile, BK=64, 4 waves, double-buffered LDS,
// 2-phase pipeline (prefetch next K-tile, counted vmcnt(8), raw barriers).
// Compact flat m-grid decoded from counts; bijective XCD-chunk swizzle.
// LDS swizzle: 16B slot s of row r holds global k-segment s ^ (r & 7).
template <int KDIM, int NDIM, int NXB, bool GATHER_A, bool RELU>
__global__ __launch_bounds__(256, 2) void gemm_kernel(
    const uint16_t* __restrict__ Abase, const uint16_t* __restrict__ Btbase,
    const float* __restrict__ bbase, uint16_t* __restrict__ Out,
    const int* __restrict__ counts, const int* __restrict__ toklist) {
    constexpr int NWG = NXB * MBMAX;   // 1136 or 568, both % 8 == 0
    constexpr int CPX = NWG / 8;
    int bid = blockIdx.x;
    int swz = (bid & 7) * CPX + (bid >> 3);
    int f = swz / NXB;            // flat m-block (compact across experts)
    int nx = swz % NXB;

    // decode (expert, local m-block) from flat index + row offset
    int e = NEXP, mloc = 0, offs = 0, n_e = 0;
    {
        int acc = 0, o = 0;
#pragma unroll
        for (int j = 0; j < NEXP; j++) {
            int c = counts[j];
            int mb = (c + 127) >> 7;
            if (e == NEXP && f < acc + mb) { e = j; mloc = f - acc; offs = o; n_e = c; }
            acc += mb; o += c;
        }
    }
    if (e == NEXP) return;
    int m0 = mloc * 128;
    int n0 = nx * 128;
    const uint16_t* Bt = Btbase + (size_t)e * NDIM * KDIM;

    __shared__ __align__(16) uint16_t As[2][128 * 64];
    __shared__ __align__(16) uint16_t Bs[2][128 * 64];

    int tid = threadIdx.x;
    int lane = tid & 63;
    int wave = tid >> 6;

    // staging: per thread 4 A-chunks + 4 B-chunks of 16B per K-tile.
    // chunk a16 = i*256 + tid -> row r = a16>>3, lds slot s = a16&7,
    // global k-segment g = s ^ (r&7)  (pre-swizzled source, linear LDS dest)
    const uint16_t* asrc[4];
    const uint16_t* bsrc[4];
#pragma unroll
    for (int i = 0; i < 4; i++) {
        int a16 = i * 256 + tid;
        int r = a16 >> 3, s = a16 & 7;
        int g = s ^ (r & 7);
        int grow;
        if (GATHER_A) {
            int idx = m0 + r;
            if (idx >= n_e) idx = 0;
            grow = toklist[offs + idx];
        } else {
            grow = offs + m0 + r;   // rows >= n_e read garbage; never stored
        }
        asrc[i] = Abase + (size_t)grow * KDIM + g * 8;
        bsrc[i] = Bt + (size_t)(n0 + r) * KDIM + g * 8;
    }

    // fragment read offsets (elements): row ar, k-seg (ks*4+qd) -> slot ^(ar&7)
    int wm = (wave >> 1) * 64;
    int wn = (wave & 1) * 64;
    int l16 = lane & 15, qd = lane >> 4;
    int o_a[4][2], o_b[4][2];
#pragma unroll
    for (int t = 0; t < 4; t++) {
        int ar = wm + t * 16 + l16;
        int br = wn + t * 16 + l16;
#pragma unroll
        for (int ks = 0; ks < 2; ks++) {
            o_a[t][ks] = ar * 64 + (((ks << 2) | qd) ^ (ar & 7)) * 8;
            o_b[t][ks] = br * 64 + (((ks << 2) | qd) ^ (br & 7)) * 8;
        }
    }

    f32x4 acc[4][4];
    f32x4 zero = {0.f, 0.f, 0.f, 0.f};
#pragma unroll
    for (int i = 0; i < 4; i++)
#pragma unroll
        for (int j = 0; j < 4; j++) acc[i][j] = zero;

    constexpr int NK = KDIM / 64;
    // prologue: stage K-tile 0 into buffer 0
#pragma unroll
    for (int i = 0; i < 4; i++) {
        gl_lds16(asrc[i], &As[0][i * 2048 + wave * 512]);
        gl_lds16(bsrc[i], &Bs[0][i * 2048 + wave * 512]);
    }

    for (int kb = 0; kb < NK; kb++) {
        int cur = kb & 1;
        int nxt = cur ^ 1;
        if (kb + 1 < NK) {
            // issue next K-tile (WAR-safe: buf[nxt] reads finished at the
            // trailing barrier of iteration kb-1)
#pragma unroll
            for (int i = 0; i < 4; i++) {
                gl_lds16(asrc[i] + (kb + 1) * 64, &As[nxt][i * 2048 + wave * 512]);
                gl_lds16(bsrc[i] + (kb + 1) * 64, &Bs[nxt][i * 2048 + wave * 512]);
            }
            // 8 newest (next tile) may stay in flight; tile kb must have landed
            asm volatile("s_waitcnt vmcnt(8)" ::: "memory");
        } else {
            asm volatile("s_waitcnt vmcnt(0)" ::: "memory");
        }
        __builtin_amdgcn_s_barrier();   // all waves' DMA for tile kb visible

        V16 af[4][2], bf[4][2];
#pragma unroll
        for (int t = 0; t < 4; t++)
#pragma unroll
            for (int ks = 0; ks < 2; ks++) {
                af[t][ks].u = *(const uint4*)(&As[cur][o_a[t][ks]]);
                bf[t][ks].u = *(const uint4*)(&Bs[cur][o_b[t][ks]]);
            }
#pragma unroll
        for (int t = 0; t < 4; t++)
#pragma unroll
            for (int u = 0; u < 4; u++)
#pragma unroll
                for (int ks = 0; ks < 2; ks++)
                    acc[t][u] = __builtin_amdgcn_mfma_f32_16x16x32_bf16(
                        af[t][ks].b, bf[u][ks].b, acc[t][u], 0, 0, 0);
        __builtin_amdgcn_s_barrier();   // all reads of buf[cur] done before reuse
    }

    // epilogue: C/D layout col=lane&15, row=(lane>>4)*4+reg
    const float* bias = bbase + (size_t)e * NDIM;
    int mrem = n_e - m0;
#pragma unroll
    for (int i = 0; i < 4; i++) {
        int rb = wm + i * 16 + qd * 4;
#pragma unroll
        for (int j = 0; j < 4; j++) {
            int col = n0 + wn + j * 16 + l16;
            float bv = bias[col];
#pragma unroll
            for (int r = 0; r < 4; r++) {
                int lr = rb + r;
                if (lr < mrem) {
                    float v = acc[i][j][r] + bv;
                    if (RELU) v = fmaxf(v, 0.f);
                    Out[(size_t)(offs + m0 + lr) * NDIM + col] = f2bf(v);
                }
            }
        }
    }
}

// ---- combine: out[t] = p0*y[pos0] + p1*y[pos1] ----
__global__ __launch_bounds__(256) void combine_kernel(const uint16_t* __restrict__ y,
                                                      const int* __restrict__ posmap,
                                                      const float* __restrict__ pair_p,
                                                      float* __restrict__ out) {
    int t = blockIdx.x;
    int d4 = threadIdx.x;
    int p0 = posmap[t * 2], p1 = posmap[t * 2 + 1];
    float w0 = pair_p[t * 2], w1 = pair_p[t * 2 + 1];
    ushort4 a = ((const ushort4*)(y + (size_t)p0 * EMBD))[d4];
    ushort4 b = ((const ushort4*)(y + (size_t)p1 * EMBD))[d4];
    float4 o;
    o.x = w0 * bf2f(a.x) + w1 * bf2f(b.x);
    o.y = w0 * bf2f(a.y) + w1 * bf2f(b.y);
    o.z = w0 * bf2f(a.z) + w1 * bf2f(b.z);
    o.w = w0 * bf2f(a.w) + w1 * bf2f(b.w);
    ((float4*)(out + (size_t)t * EMBD))[d4] = o;
}

extern "C" void kernel_launch(void* const* d_in, const int* in_sizes, int n_in,
                              void* d_out, int out_size, void* d_ws, size_t ws_size,
                              hipStream_t stream) {
    const float* x  = (const float*)d_in[0];
    const float* Wr = (const float*)d_in[1];
    const float* br = (const float*)d_in[2];
    const float* W1 = (const float*)d_in[3];
    const float* b1 = (const float*)d_in[4];
    const float* Wg = (const float*)d_in[5];
    const float* bg = (const float*)d_in[6];
    const float* W2 = (const float*)d_in[7];
    const float* b2 = (const float*)d_in[8];
    float* out = (float*)d_out;

    char* ws = (char*)d_ws;
    uint16_t* xb  = (uint16_t*)ws;                    //  8 MB
    uint16_t* h   = (uint16_t*)(ws + (8ull << 20));   // 32 MB; y aliases (h dead at L3)
    uint16_t* yb  = h;
    uint16_t* W1t = (uint16_t*)(ws + (40ull << 20));  // 32 MB; g aliases (W1t dead at L2)
    uint16_t* g   = W1t;
    uint16_t* Wgt = (uint16_t*)(ws + (72ull << 20));  // 64 MB
    uint16_t* W2t = (uint16_t*)(ws + (136ull << 20)); // 32 MB
    int* meta = (int*)(ws + (168ull << 20));
    int*   counts  = meta;                    // 8
    int*   cursors = meta + 8;                // 8
    int*   pair_e  = meta + 16;               // NPAIR
    int*   toklist = meta + 16 + NPAIR;       // NPAIR
    int*   posmap  = meta + 16 + 2 * NPAIR;   // NPAIR
    float* pair_p  = (float*)(meta + 16 + 3 * NPAIR);  // NPAIR

    hipMemsetAsync(counts, 0, 16 * sizeof(int), stream);

    fused_rt_kernel<<<RT_BLOCKS + W1_TILES + WG_TILES + W2_TILES, 256, 0, stream>>>(
        x, Wr, br, xb, counts, pair_e, pair_p, W1, Wg, W2, W1t, Wgt, W2t);
    scatter_kernel<<<NPAIR / 256, 256, 0, stream>>>(pair_e, counts, cursors, toklist, posmap);

    // layer1: [n_e,1024] x [1024,2048]
    gemm_kernel<EMBD, HIDD, 16, true, false>
        <<<16 * MBMAX, 256, 0, stream>>>(xb, W1t, b1, h, counts, toklist);
    // layer2: relu([n_e,2048] x [2048,2048])
    gemm_kernel<HIDD, HIDD, 16, false, true>
        <<<16 * MBMAX, 256, 0, stream>>>(h, Wgt, bg, g, counts, toklist);
    // layer3: [n_e,2048] x [2048,1024]
    gemm_kernel<HIDD, EMBD, 8, false, false>
        <<<8 * MBMAX, 256, 0, stream>>>(g, W2t, b2, yb, counts, toklist);
    combine_kernel<<<NTOK, 256, 0, stream>>>(yb, posmap, pair_p, out);
}